// Round 6
// baseline (1150.606 us; speedup 1.0000x reference)
//
#include <hip/hip_runtime.h>

// MyRNN: B=128, T=80, E=100, V=10000, U=512
// 8 clusters x 32 member-blocks. Cluster c owns batch rows [16c,16c+16).
// Member m owns output cols [16m,16m+16) of rk0/rk1/k1 (stationary in LDS,
// hi/lo bf16 split).
// R1: acquire/release -> buffer_inv/wbl2 thrash. Relaxed agent-scope only.
// R2/R3: 13us/round from serialized 8B far loads -> batch into regs (R4, 2.3x).
// R5: flagless 1-bit parity retry -> retry storms + t-3 ABA hole. REVERTED.
// R6: counter protocol kept (bounded), but (a) producer wave posts
//     autonomously: stores -> own s_waitcnt vmcnt(0) -> lane0 no-return
//     atomicAdd (no block barrier on the post path); (b) consumers issue the
//     32-load gather SPECULATIVELY before the poll, then after poll+barrier
//     re-load only tag-stale slots (exactly one bounded pass); (c) 2-bit step
//     tag (t&3) in each packed word's lo bits closes the ABA distance-2 hole.

typedef __attribute__((ext_vector_type(8))) short short8;
typedef __attribute__((ext_vector_type(4))) float f32x4;
typedef unsigned long long ull;

#define MFMA16(a,b,c) __builtin_amdgcn_mfma_f32_16x16x32_bf16(a,b,c,0,0,0)
#define LOAD_RLX(p)    __hip_atomic_load((p), __ATOMIC_RELAXED, __HIP_MEMORY_SCOPE_AGENT)
#define STORE_RLX(p,v) __hip_atomic_store((p), (v), __ATOMIC_RELAXED, __HIP_MEMORY_SCOPE_AGENT)
#define ADD_RLX(p,v)   __hip_atomic_fetch_add((p), (v), __ATOMIC_RELAXED, __HIP_MEMORY_SCOPE_AGENT)

__device__ __forceinline__ short f2bf(float v){
  unsigned u = __float_as_uint(v);
  u = (u + 0x7fffu + ((u >> 16) & 1u)) >> 16;   // RNE to bf16
  return (short)u;
}
__device__ __forceinline__ float bf2f(short s){
  return __uint_as_float(((unsigned)(unsigned short)s) << 16);
}
__device__ __forceinline__ float fast_tanh(float x){
  x = fminf(15.f, fmaxf(-15.f, x));
  float e = __expf(2.f * x);
  return (e - 1.f) * __builtin_amdgcn_rcpf(e + 1.f);
}

__launch_bounds__(128, 1)
__global__ void rnn_kernel(const int* __restrict__ tokens,
                           const float* __restrict__ emb,
                           const float* __restrict__ k0,
                           const float* __restrict__ rk0,
                           const float* __restrict__ b0,
                           const float* __restrict__ k1,
                           const float* __restrict__ rk1,
                           const float* __restrict__ b1,
                           const float* __restrict__ wd,
                           const float* __restrict__ bd,
                           float* __restrict__ out,
                           char* __restrict__ ws)
{
  constexpr int T = 80, E = 100, U = 512;
  const int tid  = threadIdx.x;
  const int cl   = blockIdx.x & 7;    // cluster (XCD-aligned heuristic only)
  const int mem  = blockIdx.x >> 3;   // member 0..31
  const int w    = tid >> 6;          // wave id (0/1)
  const int lane = tid & 63;
  const int m    = lane & 15;         // row (A) / col (B,C)
  const int q    = lane >> 4;         // quad 0..3

  __shared__ __align__(16) short sW[6][16][520];   // rk0 hi/lo, rk1 hi/lo, k1 hi/lo : [col][k]
  __shared__ __align__(16) short sH[2][16][520];   // h / h0 staging hi,lo : [row][k]
  __shared__ __align__(16) short sE[2][16][136];   // emb rows hi,lo (K padded to 128 w/ zeros)
  __shared__ __align__(16) short sK0[2][16][136];  // k0 slice hi,lo : [col][k] (padded)
  __shared__ int   sTok[16][80];
  __shared__ float sB0[16], sB1[16];
  __shared__ float sRed[16][8];

  int*      cnts = (int*)ws;                       // 8 counters, 64B apart (memset 0 by launch)
  unsigned* hPk  = (unsigned*)(ws + 16*1024);      // h1 packed (hi<<16 | lo&~3 | tag), [128][512]
  unsigned* h0Pk = hPk + 128*U;                    // h0 packed
  int*      cnt  = cnts + cl*16;

  // ---------------- prologue: stationary weights -> LDS ----------------
  const float* mats[3] = { rk0, rk1, k1 };
  for (int mi = 0; mi < 3; ++mi){
    const float* G = mats[mi];
    for (int i = tid; i < 16*U; i += 128){
      int k = i >> 4, c = i & 15;
      float v  = G[k*U + mem*16 + c];
      short hi = f2bf(v);
      short lo = f2bf(v - bf2f(hi));
      sW[2*mi+0][c][k] = hi;
      sW[2*mi+1][c][k] = lo;
    }
  }
  for (int i = tid; i < 2*16*136; i += 128){ ((short*)sE)[i] = 0; ((short*)sK0)[i] = 0; }
  __syncthreads();
  for (int i = tid; i < 16*E; i += 128){
    int e = i >> 4, c = i & 15;
    float v  = k0[e*U + mem*16 + c];
    short hi = f2bf(v);
    short lo = f2bf(v - bf2f(hi));
    sK0[0][c][e] = hi; sK0[1][c][e] = lo;
  }
  for (int i = tid; i < 16*T; i += 128){
    int r = i / T, t = i - r*T;
    sTok[r][t] = tokens[(cl*16 + r)*T + t];
  }
  if (tid < 16){ sB0[tid] = b0[mem*16 + tid]; sB1[tid] = b1[mem*16 + tid]; }
  __syncthreads();

  auto poll = [&](int target){
    if (tid == 0){ while (LOAD_RLX(cnt) < target) {} }
  };
  // After poll+barrier: re-load tag-stale slots (bounded: one pass suffices),
  // then unpack into sH.
  auto fix_unpack = [&](const unsigned* srcPk, ull (&r)[32], unsigned tag){
    const ull* s = (const ull*)(srcPk + cl*16*U);
    while (true){
      unsigned stale = 0u;
      #pragma unroll
      for (int j = 0; j < 32; ++j){
        unsigned lo32 = (unsigned)r[j], hi32 = (unsigned)(r[j] >> 32);
        if ((((lo32 ^ tag) | (hi32 ^ tag)) & 3u)) stale |= 1u << j;
      }
      if (!stale) break;
      #pragma unroll
      for (int j = 0; j < 32; ++j)
        if (stale & (1u << j)) r[j] = LOAD_RLX(&s[j*128 + tid]);
    }
    #pragma unroll
    for (int j = 0; j < 32; ++j){
      int i = j*128 + tid, row = i >> 8, c = (i & 255) * 2;
      unsigned p0 = (unsigned)r[j], p1 = (unsigned)(r[j] >> 32);
      *(unsigned*)&sH[0][row][c] = (p0 >> 16)     | (p1 & 0xffff0000u);
      *(unsigned*)&sH[1][row][c] = (p0 & 0xffffu) | (p1 << 16);
    }
  };

  const f32x4 zero4 = {0.f, 0.f, 0.f, 0.f};

  // ---------------- recurrence ----------------
  for (int t = 0; t < T; ++t){
    const unsigned wtag = (unsigned)t & 3u;        // tag for all writes at step t

    // speculative round-A gather (h = h1(t-1), written with tag (t-1)&3)
    ull rA[32];
    if (t > 0){
      const ull* s = (const ull*)(hPk + cl*16*U);
      #pragma unroll
      for (int j = 0; j < 32; ++j) rA[j] = LOAD_RLX(&s[j*128 + tid]);
    }
    float ev[13];
    #pragma unroll
    for (int p = 0; p < 13; ++p){
      int i = tid + p*128;
      ev[p] = (i < 16*E) ? emb[sTok[i/E][t]*E + (i % E)] : 0.f;
    }
    if (t > 0) poll(64*t);                         // = 32*(2t): all round-B(t-1) posts
    __syncthreads();
    if (t > 0) fix_unpack(hPk, rA, (unsigned)(t-1) & 3u);
    #pragma unroll
    for (int p = 0; p < 13; ++p){
      int i = tid + p*128;
      if (i < 16*E){
        int row = i / E, e = i % E;
        short hi = f2bf(ev[p]);
        short lo = f2bf(ev[p] - bf2f(hi));
        sE[0][row][e] = hi; sE[1][row][e] = lo;
      }
    }
    __syncthreads();

    // ---- round A: wave0: h0 = tanh(x@k0 + h@rk0 + b0); wave1: h@rk1 partial
    f32x4 z1a = zero4, z1b = zero4, z1c = zero4, z1d = zero4;
    if (w == 0){
      f32x4 za = zero4, zb = zero4, zc = zero4, zd = zero4;
      #pragma unroll
      for (int kk = 0; kk < 4; ++kk){
        short8 ah = *(const short8*)&sE[0][m][kk*32 + q*8];
        short8 al = *(const short8*)&sE[1][m][kk*32 + q*8];
        short8 bh = *(const short8*)&sK0[0][m][kk*32 + q*8];
        short8 bl = *(const short8*)&sK0[1][m][kk*32 + q*8];
        za = MFMA16(ah, bh, za); zb = MFMA16(al, bh, zb);
        zc = MFMA16(ah, bl, zc); zd = MFMA16(al, bl, zd);
      }
      if (t > 0){
        #pragma unroll
        for (int kk = 0; kk < 16; ++kk){
          short8 ah = *(const short8*)&sH[0][m][kk*32 + q*8];
          short8 al = *(const short8*)&sH[1][m][kk*32 + q*8];
          short8 bh = *(const short8*)&sW[0][m][kk*32 + q*8];
          short8 bl = *(const short8*)&sW[1][m][kk*32 + q*8];
          za = MFMA16(ah, bh, za); zb = MFMA16(al, bh, zb);
          zc = MFMA16(ah, bl, zc); zd = MFMA16(al, bl, zd);
        }
      }
      f32x4 z = za; z += zb; z += zc; z += zd;
      #pragma unroll
      for (int r = 0; r < 4; ++r){
        float h0v = fast_tanh(z[r] + sB0[m]);
        short hi = f2bf(h0v);
        short lo = f2bf(h0v - bf2f(hi));
        int gr = cl*16 + q*4 + r, gc = mem*16 + m;
        unsigned pk = ((unsigned)(unsigned short)hi << 16)
                    | ((unsigned)(unsigned short)lo & 0xFFFCu) | wtag;
        STORE_RLX(&h0Pk[gr*U + gc], pk);
      }
      // wave-autonomous post: own stores drained, then fire-and-forget add
      asm volatile("s_waitcnt vmcnt(0)" ::: "memory");
      if (lane == 0) ADD_RLX(cnt, 1);
    } else {
      if (t > 0){
        #pragma unroll
        for (int kk = 0; kk < 16; ++kk){
          short8 ah = *(const short8*)&sH[0][m][kk*32 + q*8];
          short8 al = *(const short8*)&sH[1][m][kk*32 + q*8];
          short8 bh = *(const short8*)&sW[2][m][kk*32 + q*8];
          short8 bl = *(const short8*)&sW[3][m][kk*32 + q*8];
          z1a = MFMA16(ah, bh, z1a); z1b = MFMA16(al, bh, z1b);
          z1c = MFMA16(ah, bl, z1c); z1d = MFMA16(al, bl, z1d);
        }
      }
    }

    // ---- round B: speculative gather of h0, poll, fix, compute h1
    ull rB[32];
    {
      const ull* s = (const ull*)(h0Pk + cl*16*U);
      #pragma unroll
      for (int j = 0; j < 32; ++j) rB[j] = LOAD_RLX(&s[j*128 + tid]);
    }
    poll(32*(2*t + 1));
    __syncthreads();
    fix_unpack(h0Pk, rB, wtag);
    __syncthreads();
    if (w == 1){
      f32x4 za = zero4, zb = zero4, zc = zero4, zd = zero4;
      #pragma unroll
      for (int kk = 0; kk < 16; ++kk){
        short8 ah = *(const short8*)&sH[0][m][kk*32 + q*8];
        short8 al = *(const short8*)&sH[1][m][kk*32 + q*8];
        short8 bh = *(const short8*)&sW[4][m][kk*32 + q*8];
        short8 bl = *(const short8*)&sW[5][m][kk*32 + q*8];
        za = MFMA16(ah, bh, za); zb = MFMA16(al, bh, zb);
        zc = MFMA16(ah, bl, zc); zd = MFMA16(al, bl, zd);
      }
      f32x4 z = za; z += zb; z += zc; z += zd;
      z += z1a; z += z1b; z += z1c; z += z1d;
      #pragma unroll
      for (int r = 0; r < 4; ++r){
        float h1v = fast_tanh(z[r] + sB1[m]);
        short hi = f2bf(h1v);
        short lo = f2bf(h1v - bf2f(hi));
        int gr = cl*16 + q*4 + r, gc = mem*16 + m;
        unsigned pk = ((unsigned)(unsigned short)hi << 16)
                    | ((unsigned)(unsigned short)lo & 0xFFFCu) | wtag;
        STORE_RLX(&hPk[gr*U + gc], pk);
      }
      asm volatile("s_waitcnt vmcnt(0)" ::: "memory");
      if (lane == 0) ADD_RLX(cnt, 1);
    }
    // no trailing barrier: loop-top barrier (after spec issue + poll) aligns waves
  }

  // ---------------- epilogue: logits = h@wd + bd ; sigmoid ----------------
  if (mem == 0){
    poll(64*T);                                    // all round-B(79) posts
    __syncthreads();
    ull rE[32];
    {
      const ull* s = (const ull*)(hPk + cl*16*U);
      #pragma unroll
      for (int j = 0; j < 32; ++j) rE[j] = LOAD_RLX(&s[j*128 + tid]);
    }
    fix_unpack(hPk, rE, (unsigned)(T-1) & 3u);     // t=79 -> tag 3
    __syncthreads();
    {
      int row = tid >> 3, seg = tid & 7;
      float acc = 0.f;
      for (int u = seg*64; u < seg*64 + 64; ++u){
        float hv = bf2f(sH[0][row][u]) + bf2f(sH[1][row][u]);
        acc += hv * wd[u];
      }
      sRed[row][seg] = acc;
    }
    __syncthreads();
    if (tid < 16){
      float s = bd[0];
      #pragma unroll
      for (int j = 0; j < 8; ++j) s += sRed[tid][j];
      out[cl*16 + tid] = 1.f / (1.f + __expf(-s));
    }
  }
}

extern "C" void kernel_launch(void* const* d_in, const int* in_sizes, int n_in,
                              void* d_out, int out_size, void* d_ws, size_t ws_size,
                              hipStream_t stream) {
  const int*   tokens = (const int*)  d_in[0];
  const float* emb    = (const float*)d_in[1];
  const float* k0     = (const float*)d_in[2];
  const float* rk0    = (const float*)d_in[3];
  const float* b0     = (const float*)d_in[4];
  const float* k1     = (const float*)d_in[5];
  const float* rk1    = (const float*)d_in[6];
  const float* b1     = (const float*)d_in[7];
  const float* wd     = (const float*)d_in[8];
  const float* bd     = (const float*)d_in[9];

  // Zero the per-cluster counters (0xAA poison breaks monotonic arithmetic).
  hipMemsetAsync(d_ws, 0, 4096, stream);

  hipLaunchKernelGGL(rnn_kernel, dim3(256), dim3(128), 0, stream,
                     tokens, emb, k0, rk0, b0, k1, rk1, b1, wd, bd,
                     (float*)d_out, (char*)d_ws);
}

// Round 7
// 781.554 us; speedup vs baseline: 1.4722x; 1.4722x over previous
//
#include <hip/hip_runtime.h>

// MyRNN: B=128, T=80, E=100, V=10000, U=512
// 8 clusters x 32 member-blocks, formed DYNAMICALLY by physical XCD
// (s_getreg HW_REG_XCC_ID + atomic slot grab): with 156KB LDS -> 1 block/CU,
// grid 256 fills all CUs, so each XCD hosts exactly 32 blocks -> a cluster's
// members share one L2 BY CONSTRUCTION (G16-sound, no mapping assumption).
// Cluster c owns batch rows [16c,16c+16); member m owns cols [16m,16m+16) of
// rk0/rk1/k1 (stationary in LDS, hi/lo bf16 split).
// R1: acquire/release -> buffer_inv/wbl2 thrash. Counter stays relaxed/MALL.
// R2-R6: ALL protocol variants pinned at 5.5-7us/exchange -> the invariant
//   was the DATA path: 8B uncached MALL transactions (~1M/exchange).
// R7: data path moved to XCD-local L2: plain stores (L1 is write-through),
//   global_load_dwordx4 sc0 gathers (bypass L1, hit shared L2). Counter/post
//   protocol = R4-proven MALL path. No tags (full lo precision). End-of-kernel
//   __threadfence flushes L2 exchange lines for graph-replay hygiene.

typedef __attribute__((ext_vector_type(8))) short short8;
typedef __attribute__((ext_vector_type(4))) float f32x4;

#define MFMA16(a,b,c) __builtin_amdgcn_mfma_f32_16x16x32_bf16(a,b,c,0,0,0)
#define LOAD_RLX(p)    __hip_atomic_load((p), __ATOMIC_RELAXED, __HIP_MEMORY_SCOPE_AGENT)
#define ADD_RLX(p,v)   __hip_atomic_fetch_add((p), (v), __ATOMIC_RELAXED, __HIP_MEMORY_SCOPE_AGENT)

__device__ __forceinline__ short f2bf(float v){
  unsigned u = __float_as_uint(v);
  u = (u + 0x7fffu + ((u >> 16) & 1u)) >> 16;   // RNE to bf16
  return (short)u;
}
__device__ __forceinline__ float bf2f(short s){
  return __uint_as_float(((unsigned)(unsigned short)s) << 16);
}
__device__ __forceinline__ float fast_tanh(float x){
  x = fminf(15.f, fmaxf(-15.f, x));
  float e = __expf(2.f * x);
  return (e - 1.f) * __builtin_amdgcn_rcpf(e + 1.f);
}

__launch_bounds__(128, 1)
__global__ void rnn_kernel(const int* __restrict__ tokens,
                           const float* __restrict__ emb,
                           const float* __restrict__ k0,
                           const float* __restrict__ rk0,
                           const float* __restrict__ b0,
                           const float* __restrict__ k1,
                           const float* __restrict__ rk1,
                           const float* __restrict__ b1,
                           const float* __restrict__ wd,
                           const float* __restrict__ bd,
                           float* __restrict__ out,
                           char* __restrict__ ws)
{
  constexpr int T = 80, E = 100, U = 512;
  const int tid  = threadIdx.x;
  const int w    = tid >> 6;          // wave id (0/1)
  const int lane = tid & 63;
  const int m    = lane & 15;         // row (A) / col (B,C)
  const int q    = lane >> 4;         // quad 0..3

  __shared__ __align__(16) short sW[6][16][520];   // rk0 hi/lo, rk1 hi/lo, k1 hi/lo : [col][k]
  __shared__ __align__(16) short sH[2][16][520];   // h / h0 staging hi,lo : [row][k]
  __shared__ __align__(16) short sE[2][16][136];   // emb rows hi,lo (K padded to 128 w/ zeros)
  __shared__ __align__(16) short sK0[2][16][136];  // k0 slice hi,lo : [col][k] (padded)
  __shared__ int   sTok[16][80];
  __shared__ float sB0[16], sB1[16];
  __shared__ float sRed[16][8];
  __shared__ int   sReg[2];

  int*      cnts   = (int*)ws;                     // 8 counters, 64B stride (MALL path)
  int*      regCnt = (int*)(ws + 512);             // 8 registration counters, 64B stride
  unsigned* hPk    = (unsigned*)(ws + 16*1024);    // h1 packed (hi<<16|lo), [128][512]
  unsigned* h0Pk   = hPk + 128*U;                  // h0 packed

  // -------- dynamic cluster formation: cluster id = physical XCD --------
  int xcc;
  asm volatile("s_getreg_b32 %0, hwreg(HW_REG_XCC_ID)" : "=s"(xcc));
  if (tid == 0){
    int slot = ADD_RLX(regCnt + (xcc & 7)*16, 1);  // 0..31 within this XCD
    sReg[0] = xcc & 7;
    sReg[1] = slot;
  }
  __syncthreads();
  const int cl  = sReg[0];
  const int mem = sReg[1];
  int* cnt = cnts + cl*16;

  // ---------------- prologue: stationary weights -> LDS ----------------
  const float* mats[3] = { rk0, rk1, k1 };
  for (int mi = 0; mi < 3; ++mi){
    const float* G = mats[mi];
    for (int i = tid; i < 16*U; i += 128){
      int k = i >> 4, c = i & 15;
      float v  = G[k*U + mem*16 + c];
      short hi = f2bf(v);
      short lo = f2bf(v - bf2f(hi));
      sW[2*mi+0][c][k] = hi;
      sW[2*mi+1][c][k] = lo;
    }
  }
  for (int i = tid; i < 2*16*136; i += 128){ ((short*)sE)[i] = 0; ((short*)sK0)[i] = 0; }
  __syncthreads();
  for (int i = tid; i < 16*E; i += 128){
    int e = i >> 4, c = i & 15;
    float v  = k0[e*U + mem*16 + c];
    short hi = f2bf(v);
    short lo = f2bf(v - bf2f(hi));
    sK0[0][c][e] = hi; sK0[1][c][e] = lo;
  }
  for (int i = tid; i < 16*T; i += 128){
    int r = i / T, t = i - r*T;
    sTok[r][t] = tokens[(cl*16 + r)*T + t];
  }
  if (tid < 16){ sB0[tid] = b0[mem*16 + tid]; sB1[tid] = b1[mem*16 + tid]; }
  __syncthreads();

  auto poll = [&](int target){
    if (tid == 0){ while (LOAD_RLX(cnt) < target) {} }
  };
  // L2 gather: 16x dwordx4 sc0 (bypass L1, hit XCD-shared L2), then unpack.
  auto gather = [&](const unsigned* srcPk){
    const uint4* s = (const uint4*)(srcPk + cl*16*U);   // 2048 uint4 = 32 KB
    uint4 r[16];
    #pragma unroll
    for (int j = 0; j < 16; ++j)
      asm volatile("global_load_dwordx4 %0, %1, off sc0"
                   : "=v"(r[j]) : "v"(&s[j*128 + tid]));
    asm volatile("s_waitcnt vmcnt(0)" ::: "memory");
    #pragma unroll
    for (int j = 0; j < 16; ++j){
      int i = j*128 + tid, row = i >> 7, c = (i & 127) * 4;
      unsigned h0 = (r[j].x >> 16)     | (r[j].y & 0xffff0000u);
      unsigned h1 = (r[j].z >> 16)     | (r[j].w & 0xffff0000u);
      unsigned l0 = (r[j].x & 0xffffu) | (r[j].y << 16);
      unsigned l1 = (r[j].z & 0xffffu) | (r[j].w << 16);
      uint2 hh; hh.x = h0; hh.y = h1;
      uint2 ll; ll.x = l0; ll.y = l1;
      *(uint2*)&sH[0][row][c] = hh;
      *(uint2*)&sH[1][row][c] = ll;
    }
  };

  const f32x4 zero4 = {0.f, 0.f, 0.f, 0.f};

  // ---------------- recurrence ----------------
  for (int t = 0; t < T; ++t){
    // stage emb rows into regs early (independent of exchange)
    float ev[13];
    #pragma unroll
    for (int p = 0; p < 13; ++p){
      int i = tid + p*128;
      ev[p] = (i < 16*E) ? emb[sTok[i/E][t]*E + (i % E)] : 0.f;
    }
    if (t > 0) poll(64*t);                 // all round-B(t-1) posts
    __syncthreads();
    if (t > 0) gather(hPk);
    #pragma unroll
    for (int p = 0; p < 13; ++p){
      int i = tid + p*128;
      if (i < 16*E){
        int row = i / E, e = i % E;
        short hi = f2bf(ev[p]);
        short lo = f2bf(ev[p] - bf2f(hi));
        sE[0][row][e] = hi; sE[1][row][e] = lo;
      }
    }
    __syncthreads();

    // ---- round A: wave0: h0 = tanh(x@k0 + h@rk0 + b0); wave1: h@rk1 partial
    f32x4 z1a = zero4, z1b = zero4, z1c = zero4, z1d = zero4;
    if (w == 0){
      f32x4 za = zero4, zb = zero4, zc = zero4, zd = zero4;
      #pragma unroll
      for (int kk = 0; kk < 4; ++kk){
        short8 ah = *(const short8*)&sE[0][m][kk*32 + q*8];
        short8 al = *(const short8*)&sE[1][m][kk*32 + q*8];
        short8 bh = *(const short8*)&sK0[0][m][kk*32 + q*8];
        short8 bl = *(const short8*)&sK0[1][m][kk*32 + q*8];
        za = MFMA16(ah, bh, za); zb = MFMA16(al, bh, zb);
        zc = MFMA16(ah, bl, zc); zd = MFMA16(al, bl, zd);
      }
      if (t > 0){
        #pragma unroll
        for (int kk = 0; kk < 16; ++kk){
          short8 ah = *(const short8*)&sH[0][m][kk*32 + q*8];
          short8 al = *(const short8*)&sH[1][m][kk*32 + q*8];
          short8 bh = *(const short8*)&sW[0][m][kk*32 + q*8];
          short8 bl = *(const short8*)&sW[1][m][kk*32 + q*8];
          za = MFMA16(ah, bh, za); zb = MFMA16(al, bh, zb);
          zc = MFMA16(ah, bl, zc); zd = MFMA16(al, bl, zd);
        }
      }
      f32x4 z = za; z += zb; z += zc; z += zd;
      #pragma unroll
      for (int r = 0; r < 4; ++r){
        float h0v = fast_tanh(z[r] + sB0[m]);
        short hi = f2bf(h0v);
        short lo = f2bf(h0v - bf2f(hi));
        int gr = cl*16 + q*4 + r, gc = mem*16 + m;
        unsigned pk = ((unsigned)(unsigned short)hi << 16) | (unsigned short)lo;
        h0Pk[gr*U + gc] = pk;              // plain store -> write-through to XCD L2
      }
      // wave-autonomous post: own stores in L2, then fire-and-forget MALL add
      asm volatile("s_waitcnt vmcnt(0)" ::: "memory");
      if (lane == 0) ADD_RLX(cnt, 1);
    } else {
      if (t > 0){
        #pragma unroll
        for (int kk = 0; kk < 16; ++kk){
          short8 ah = *(const short8*)&sH[0][m][kk*32 + q*8];
          short8 al = *(const short8*)&sH[1][m][kk*32 + q*8];
          short8 bh = *(const short8*)&sW[2][m][kk*32 + q*8];
          short8 bl = *(const short8*)&sW[3][m][kk*32 + q*8];
          z1a = MFMA16(ah, bh, z1a); z1b = MFMA16(al, bh, z1b);
          z1c = MFMA16(ah, bl, z1c); z1d = MFMA16(al, bl, z1d);
        }
      }
    }

    // ---- round B: h1 = tanh(h0@k1 + h@rk1 + b1)
    poll(32*(2*t + 1));
    __syncthreads();
    gather(h0Pk);
    __syncthreads();
    if (w == 1){
      f32x4 za = zero4, zb = zero4, zc = zero4, zd = zero4;
      #pragma unroll
      for (int kk = 0; kk < 16; ++kk){
        short8 ah = *(const short8*)&sH[0][m][kk*32 + q*8];
        short8 al = *(const short8*)&sH[1][m][kk*32 + q*8];
        short8 bh = *(const short8*)&sW[4][m][kk*32 + q*8];
        short8 bl = *(const short8*)&sW[5][m][kk*32 + q*8];
        za = MFMA16(ah, bh, za); zb = MFMA16(al, bh, zb);
        zc = MFMA16(ah, bl, zc); zd = MFMA16(al, bl, zd);
      }
      f32x4 z = za; z += zb; z += zc; z += zd;
      z += z1a; z += z1b; z += z1c; z += z1d;
      #pragma unroll
      for (int r = 0; r < 4; ++r){
        float h1v = fast_tanh(z[r] + sB1[m]);
        short hi = f2bf(h1v);
        short lo = f2bf(h1v - bf2f(hi));
        int gr = cl*16 + q*4 + r, gc = mem*16 + m;
        unsigned pk = ((unsigned)(unsigned short)hi << 16) | (unsigned short)lo;
        hPk[gr*U + gc] = pk;               // plain store -> XCD L2
      }
      asm volatile("s_waitcnt vmcnt(0)" ::: "memory");
      if (lane == 0) ADD_RLX(cnt, 1);
    }
    // no trailing barrier: loop-top poll+barrier aligns waves
  }

  // ---------------- epilogue: logits = h@wd + bd ; sigmoid ----------------
  if (mem == 0){
    poll(64*T);
    __syncthreads();
    gather(hPk);
    __syncthreads();
    {
      int row = tid >> 3, seg = tid & 7;
      float acc = 0.f;
      for (int u = seg*64; u < seg*64 + 64; ++u){
        float hv = bf2f(sH[0][row][u]) + bf2f(sH[1][row][u]);
        acc += hv * wd[u];
      }
      sRed[row][seg] = acc;
    }
    __syncthreads();
    if (tid < 16){
      float s = bd[0];
      #pragma unroll
      for (int j = 0; j < 8; ++j) s += sRed[tid][j];
      out[cl*16 + tid] = 1.f / (1.f + __expf(-s));
    }
  }

  // replay hygiene: flush/invalidate this XCD's L2 exchange lines so no stale
  // dirty copies survive into the next graph replay (one-time cost)
  __threadfence();
}

extern "C" void kernel_launch(void* const* d_in, const int* in_sizes, int n_in,
                              void* d_out, int out_size, void* d_ws, size_t ws_size,
                              hipStream_t stream) {
  const int*   tokens = (const int*)  d_in[0];
  const float* emb    = (const float*)d_in[1];
  const float* k0     = (const float*)d_in[2];
  const float* rk0    = (const float*)d_in[3];
  const float* b0     = (const float*)d_in[4];
  const float* k1     = (const float*)d_in[5];
  const float* rk1    = (const float*)d_in[6];
  const float* b1     = (const float*)d_in[7];
  const float* wd     = (const float*)d_in[8];
  const float* bd     = (const float*)d_in[9];

  // Zero sync + registration counters (0xAA poison breaks monotonic arith).
  hipMemsetAsync(d_ws, 0, 4096, stream);

  hipLaunchKernelGGL(rnn_kernel, dim3(256), dim3(128), 0, stream,
                     tokens, emb, k0, rk0, b0, k1, rk1, b1, wd, bd,
                     (float*)d_out, (char*)d_ws);
}